// Round 8
// baseline (407.622 us; speedup 1.0000x reference)
//
#include <hip/hip_runtime.h>

#define NNODES 50000
#define NEDGES 640000
#define D 128

typedef unsigned short u16;
typedef unsigned int u32;
typedef __bf16 bf16x8 __attribute__((ext_vector_type(8)));
typedef float f32x4 __attribute__((ext_vector_type(4)));
union AB { uint4 u4; bf16x8 f; };

__device__ __forceinline__ u16 f2b(float f) {
    u32 u = __float_as_uint(f);
    return (u16)((u + 0x7fffu + ((u >> 16) & 1u)) >> 16);
}
__device__ __forceinline__ u32 pack2(float lo, float hi) {
    return (u32)f2b(lo) | ((u32)f2b(hi) << 16);
}
__device__ __forceinline__ float blo(u32 v) { return __uint_as_float(v << 16); }
__device__ __forceinline__ float bhi(u32 v) { return __uint_as_float(v & 0xffff0000u); }

__device__ __forceinline__ void acc8(float* a, uint4 v) {
    a[0] += blo(v.x); a[1] += bhi(v.x);
    a[2] += blo(v.y); a[3] += bhi(v.y);
    a[4] += blo(v.z); a[5] += bhi(v.z);
    a[6] += blo(v.w); a[7] += bhi(v.w);
}

// ---------------- CSR build ----------------

__global__ void k_hist(const int* __restrict__ dst, int* __restrict__ cnt) {
    int e = blockIdx.x * 256 + threadIdx.x;
    if (e < NEDGES) atomicAdd(&cnt[dst[e]], 1);
}

__global__ void k_scan1(const int* __restrict__ cnt, int* __restrict__ rp,
                        int* __restrict__ bsum) {
    __shared__ int s[256];
    int tid = threadIdx.x;
    int i = blockIdx.x * 256 + tid;
    int v = (i < NNODES) ? cnt[i] : 0;
    s[tid] = v;
    __syncthreads();
    for (int off = 1; off < 256; off <<= 1) {
        int t = (tid >= off) ? s[tid - off] : 0;
        __syncthreads();
        s[tid] += t;
        __syncthreads();
    }
    if (i < NNODES) rp[i] = s[tid] - v;
    if (tid == 255) bsum[blockIdx.x] = s[255];
}

__global__ void k_scan2(int* __restrict__ bsum, int nb) {
    __shared__ int s[256];
    int tid = threadIdx.x;
    int v = (tid < nb) ? bsum[tid] : 0;
    s[tid] = v;
    __syncthreads();
    for (int off = 1; off < 256; off <<= 1) {
        int t = (tid >= off) ? s[tid - off] : 0;
        __syncthreads();
        s[tid] += t;
        __syncthreads();
    }
    if (tid < nb) bsum[tid] = s[tid] - v;
}

__global__ void k_add(int* __restrict__ rp, const int* __restrict__ bsum) {
    int i = blockIdx.x * 256 + threadIdx.x;
    if (i < NNODES) rp[i] += bsum[blockIdx.x];
    if (i == 0) rp[NNODES] = NEDGES;
}

__global__ void k_scatter(const int* __restrict__ src, const int* __restrict__ dst,
                          const int* __restrict__ rp, int* __restrict__ cnt,
                          int* __restrict__ srcs) {
    int e = blockIdx.x * 256 + threadIdx.x;
    if (e < NEDGES) {
        int dn = dst[e];
        int old = atomicSub(&cnt[dn], 1);
        srcs[rp[dn] + old - 1] = src[e];
    }
}

// ---------------- weight prep (transpose->bf16) + x conversion, merged ----------------
__global__ void k_prep(const float* __restrict__ W1, const float* __restrict__ W2,
                       const float* __restrict__ fw, const float* __restrict__ x,
                       u16* __restrict__ wT1, u16* __restrict__ wT2,
                       u16* __restrict__ fwTc, u32* __restrict__ xb) {
    int idx = blockIdx.x * 256 + threadIdx.x;  // grid covers NNODES*64
    if (idx < 3 * 16384) {
        int l = idx >> 14, r = idx & 16383, n = r >> 7, k = r & 127;
        wT1[idx] = f2b(W1[l * 16384 + k * 128 + n]);
        wT2[idx] = f2b(W2[l * 16384 + k * 128 + n]);
    }
    if (idx < 4 * 16384) {
        int ch = idx >> 14, r = idx & 16383, n = r >> 7, k = r & 127;
        fwTc[idx] = f2b(fw[(ch * 128 + k) * 128 + n]);
    }
    if (idx < NNODES * 64) {
        float2 v = ((const float2*)x)[idx];
        xb[idx] = pack2(v.x, v.y);
    }
}

// ---------------- aggregation (unchanged from round 5) ----------------
__global__ void k_agg(const uint4* __restrict__ h4, const int* __restrict__ rp,
                      const int* __restrict__ srcs, const float* __restrict__ epsp,
                      uint4* __restrict__ z4) {
    int tid = threadIdx.x;
    int c = tid & 15;
    int node = (blockIdx.x * 256 + tid) >> 4;
    int gbase = tid & 48;
    float sc = 1.0f + epsp[0];

    uint4 sv = h4[node * 16 + c];
    float acc[8];
    acc[0] = sc * blo(sv.x); acc[1] = sc * bhi(sv.x);
    acc[2] = sc * blo(sv.y); acc[3] = sc * bhi(sv.y);
    acc[4] = sc * blo(sv.z); acc[5] = sc * bhi(sv.z);
    acc[6] = sc * blo(sv.w); acc[7] = sc * bhi(sv.w);

    int beg = rp[node], end = rp[node + 1];
    for (int base = beg; base < end; base += 16) {
        int n = end - base; if (n > 16) n = 16;
        int myidx = (base + c < end) ? srcs[base + c] : 0;
        int j = 0;
        for (; j + 8 <= n; j += 8) {
            int s0 = __shfl(myidx, gbase + j + 0, 64);
            int s1 = __shfl(myidx, gbase + j + 1, 64);
            int s2 = __shfl(myidx, gbase + j + 2, 64);
            int s3 = __shfl(myidx, gbase + j + 3, 64);
            int s4 = __shfl(myidx, gbase + j + 4, 64);
            int s5 = __shfl(myidx, gbase + j + 5, 64);
            int s6 = __shfl(myidx, gbase + j + 6, 64);
            int s7 = __shfl(myidx, gbase + j + 7, 64);
            uint4 v0 = h4[s0 * 16 + c]; uint4 v1 = h4[s1 * 16 + c];
            uint4 v2 = h4[s2 * 16 + c]; uint4 v3 = h4[s3 * 16 + c];
            uint4 v4 = h4[s4 * 16 + c]; uint4 v5 = h4[s5 * 16 + c];
            uint4 v6 = h4[s6 * 16 + c]; uint4 v7 = h4[s7 * 16 + c];
            acc8(acc, v0); acc8(acc, v1); acc8(acc, v2); acc8(acc, v3);
            acc8(acc, v4); acc8(acc, v5); acc8(acc, v6); acc8(acc, v7);
        }
        for (; j + 4 <= n; j += 4) {
            int s0 = __shfl(myidx, gbase + j + 0, 64);
            int s1 = __shfl(myidx, gbase + j + 1, 64);
            int s2 = __shfl(myidx, gbase + j + 2, 64);
            int s3 = __shfl(myidx, gbase + j + 3, 64);
            uint4 v0 = h4[s0 * 16 + c]; uint4 v1 = h4[s1 * 16 + c];
            uint4 v2 = h4[s2 * 16 + c]; uint4 v3 = h4[s3 * 16 + c];
            acc8(acc, v0); acc8(acc, v1); acc8(acc, v2); acc8(acc, v3);
        }
        for (; j < n; ++j) {
            int s0 = __shfl(myidx, gbase + j, 64);
            uint4 v0 = h4[s0 * 16 + c];
            acc8(acc, v0);
        }
    }

    uint4 o;
    o.x = pack2(acc[0], acc[1]); o.y = pack2(acc[2], acc[3]);
    o.z = pack2(acc[4], acc[5]); o.w = pack2(acc[6], acc[7]);
    z4[node * 16 + c] = o;
}

// ---------------- per-wave MLP with deep load pipelining ----------------
// Each wave owns 16 rows. All a-frags + 4 cols of b-frags issued upfront
// (~20 independent vmem loads in flight); b-frags rotate through bb[col&3],
// reloading col+4 after consumption. launch_bounds(256,3): 12 waves/CU
// (matches the 3125-wave grid), VGPR cap 170.
#define SROW 136
__launch_bounds__(256, 3)
__global__ void k_mlp(const u16* __restrict__ A, const u16* __restrict__ wT1g,
                      const float* __restrict__ b1, const u16* __restrict__ wT2g,
                      const float* __restrict__ b2, u16* __restrict__ H) {
    __shared__ u16 scratch[4][16 * SROW];  // 4 x 4.25 KB
    int tid = threadIdx.x;
    int wave = tid >> 6, lane = tid & 63, l16 = lane & 15, quad = lane >> 4;
    int wid = blockIdx.x * 4 + wave;
    if (wid * 16 >= NNODES) return;
    int r0 = wid * 16;
    u16* sc = scratch[wave];

    // burst: all independent loads issued before any consumer
    AB a[4];
#pragma unroll
    for (int kb = 0; kb < 4; ++kb)
        a[kb].u4 = *(const uint4*)&A[(r0 + l16) * 128 + kb * 32 + quad * 8];
    AB bb[4][4];
#pragma unroll
    for (int p = 0; p < 4; ++p)
#pragma unroll
        for (int kb = 0; kb < 4; ++kb)
            bb[p][kb].u4 = *(const uint4*)&wT1g[(p * 16 + l16) * 128 + kb * 32 + quad * 8];

    f32x4 acc[8];
#pragma unroll
    for (int col = 0; col < 8; ++col) {
        float bv = b1[col * 16 + l16];
        acc[col] = (f32x4){bv, bv, bv, bv};
    }
#pragma unroll
    for (int col = 0; col < 8; ++col) {
#pragma unroll
        for (int kb = 0; kb < 4; ++kb)
            acc[col] = __builtin_amdgcn_mfma_f32_16x16x32_bf16(a[kb].f, bb[col & 3][kb].f, acc[col], 0, 0, 0);
        if (col < 4) {
#pragma unroll
            for (int kb = 0; kb < 4; ++kb)
                bb[col & 3][kb].u4 =
                    *(const uint4*)&wT1g[((col + 4) * 16 + l16) * 128 + kb * 32 + quad * 8];
        }
    }

    // prefetch W2 cols 0-3 now; overlaps the T LDS round-trip below
    AB cc[4][4];
#pragma unroll
    for (int p = 0; p < 4; ++p)
#pragma unroll
        for (int kb = 0; kb < 4; ++kb)
            cc[p][kb].u4 = *(const uint4*)&wT2g[(p * 16 + l16) * 128 + kb * 32 + quad * 8];

    // T = relu -> scratch (C-layout scalar stores)
#pragma unroll
    for (int col = 0; col < 8; ++col)
#pragma unroll
        for (int r = 0; r < 4; ++r)
            sc[(quad * 4 + r) * SROW + col * 16 + l16] = f2b(fmaxf(acc[col][r], 0.f));

    // A-frags for GEMM2 (same wave; DS in-order)
    AB a2[4];
#pragma unroll
    for (int kb = 0; kb < 4; ++kb)
        a2[kb].u4 = *(const uint4*)&sc[l16 * SROW + kb * 32 + quad * 8];

#pragma unroll
    for (int col = 0; col < 8; ++col) {
        float bv = b2[col * 16 + l16];
        acc[col] = (f32x4){bv, bv, bv, bv};
    }
#pragma unroll
    for (int col = 0; col < 8; ++col) {
#pragma unroll
        for (int kb = 0; kb < 4; ++kb)
            acc[col] = __builtin_amdgcn_mfma_f32_16x16x32_bf16(a2[kb].f, cc[col & 3][kb].f, acc[col], 0, 0, 0);
        if (col < 4) {
#pragma unroll
            for (int kb = 0; kb < 4; ++kb)
                cc[col & 3][kb].u4 =
                    *(const uint4*)&wT2g[((col + 4) * 16 + l16) * 128 + kb * 32 + quad * 8];
        }
    }

    // H = relu -> scratch -> coalesced global (16 rows x 16 chunks = 4 passes)
#pragma unroll
    for (int col = 0; col < 8; ++col)
#pragma unroll
        for (int r = 0; r < 4; ++r)
            sc[(quad * 4 + r) * SROW + col * 16 + l16] = f2b(fmaxf(acc[col][r], 0.f));

#pragma unroll
    for (int p = 0; p < 4; ++p) {
        int idx = p * 64 + lane;       // 0..255
        int row = idx >> 4, ch = idx & 15;
        uint4 v = *(const uint4*)&sc[row * SROW + ch * 8];
        *(uint4*)&H[(r0 + row) * 128 + ch * 8] = v;
    }
}

// ---------------- per-wave final with all-input burst ----------------
__launch_bounds__(256, 3)
__global__ void k_final(const u16* __restrict__ xb, const u16* __restrict__ h1,
                        const u16* __restrict__ h2b, const u16* __restrict__ h3,
                        const u16* __restrict__ fwTc, const float* __restrict__ fb,
                        float* __restrict__ out) {
    int tid = threadIdx.x;
    int wave = tid >> 6, lane = tid & 63, l16 = lane & 15, quad = lane >> 4;
    int wid = blockIdx.x * 4 + wave;
    if (wid * 16 >= NNODES) return;
    int r0 = wid * 16;

    const u16* chin[4] = {xb, h1, h2b, h3};

    // burst: ALL 16 a-frags (4 inputs x 4 kb) in flight at once
    AB a[4][4];
#pragma unroll
    for (int chn = 0; chn < 4; ++chn)
#pragma unroll
        for (int kb = 0; kb < 4; ++kb)
            a[chn][kb].u4 = *(const uint4*)&chin[chn][(r0 + l16) * 128 + kb * 32 + quad * 8];

    // 2-deep b-frag rotation over the flat 32-step (chn,col) loop
    AB bb[2][4];
#pragma unroll
    for (int p = 0; p < 2; ++p)
#pragma unroll
        for (int kb = 0; kb < 4; ++kb)
            bb[p][kb].u4 = *(const uint4*)&fwTc[(p & 7) * 16 * 128 + ((p >> 3) * 16384) + l16 * 128 + kb * 32 + quad * 8];

    f32x4 acc[8];
#pragma unroll
    for (int col = 0; col < 8; ++col) {
        float bv = fb[col * 16 + l16];
        acc[col] = (f32x4){bv, bv, bv, bv};
    }

#pragma unroll
    for (int it = 0; it < 32; ++it) {
        int chn = it >> 3, col = it & 7;
#pragma unroll
        for (int kb = 0; kb < 4; ++kb)
            acc[col] = __builtin_amdgcn_mfma_f32_16x16x32_bf16(a[chn][kb].f, bb[it & 1][kb].f, acc[col], 0, 0, 0);
        if (it + 2 < 32) {
            int jt = it + 2;
            int jchn = jt >> 3, jcol = jt & 7;
#pragma unroll
            for (int kb = 0; kb < 4; ++kb)
                bb[it & 1][kb].u4 =
                    *(const uint4*)&fwTc[jchn * 16384 + (jcol * 16 + l16) * 128 + kb * 32 + quad * 8];
        }
    }

#pragma unroll
    for (int col = 0; col < 8; ++col)
#pragma unroll
        for (int r = 0; r < 4; ++r)
            out[(r0 + quad * 4 + r) * 128 + col * 16 + l16] = acc[col][r];
}

extern "C" void kernel_launch(void* const* d_in, const int* in_sizes, int n_in,
                              void* d_out, int out_size, void* d_ws, size_t ws_size,
                              hipStream_t stream) {
    const float* x   = (const float*)d_in[0];
    const int*   ei  = (const int*)d_in[1];
    const float* W1  = (const float*)d_in[2];
    const float* b1  = (const float*)d_in[3];
    const float* W2  = (const float*)d_in[4];
    const float* b2  = (const float*)d_in[5];
    const float* eps = (const float*)d_in[6];
    const float* fw  = (const float*)d_in[7];
    const float* fb  = (const float*)d_in[8];
    float* out = (float*)d_out;

    const int* srcA = ei;
    const int* dstA = ei + NEDGES;

    char* p = (char*)d_ws;
    size_t off = 0;
    auto take = [&](size_t bytes) {
        char* r = p + off;
        off = (off + bytes + 255) & ~(size_t)255;
        return r;
    };
    int* rp   = (int*)take((NNODES + 1) * sizeof(int));
    int* cnt  = (int*)take(NNODES * sizeof(int));
    int* bsum = (int*)take(256 * sizeof(int));
    int* srcs = (int*)take(NEDGES * sizeof(int));
    u16* wT1  = (u16*)take(3 * 16384 * sizeof(u16));
    u16* wT2  = (u16*)take(3 * 16384 * sizeof(u16));
    u16* fwTc = (u16*)take(4 * 16384 * sizeof(u16));
    u16* xb   = (u16*)take((size_t)NNODES * D * sizeof(u16));
    u16* zb   = (u16*)take((size_t)NNODES * D * sizeof(u16));
    u16* hb1  = (u16*)take((size_t)NNODES * D * sizeof(u16));
    u16* hb2  = (u16*)take((size_t)NNODES * D * sizeof(u16));
    u16* hb3  = (u16*)take((size_t)NNODES * D * sizeof(u16));
    (void)ws_size; (void)in_sizes; (void)n_in; (void)out_size;

    hipMemsetAsync(cnt, 0, NNODES * sizeof(int), stream);

    int nb = (NNODES + 255) / 256;
    k_hist<<<(NEDGES + 255) / 256, 256, 0, stream>>>(dstA, cnt);
    k_scan1<<<nb, 256, 0, stream>>>(cnt, rp, bsum);
    k_scan2<<<1, 256, 0, stream>>>(bsum, nb);
    k_add<<<nb, 256, 0, stream>>>(rp, bsum);
    k_scatter<<<(NEDGES + 255) / 256, 256, 0, stream>>>(srcA, dstA, rp, cnt, srcs);
    k_prep<<<(NNODES * 64 + 255) / 256, 256, 0, stream>>>(W1, W2, fw, x, wT1, wT2, fwTc, (u32*)xb);

    const u16* hin = xb;
    u16* houts[3] = {hb1, hb2, hb3};
    int gw = (3125 + 3) / 4;  // 782 blocks of 4 waves (16 rows each)
    for (int l = 0; l < 3; ++l) {
        k_agg<<<NNODES * 16 / 256, 256, 0, stream>>>((const uint4*)hin, rp, srcs, eps + l, (uint4*)zb);
        k_mlp<<<gw, 256, 0, stream>>>(zb, wT1 + l * 16384, b1 + l * D,
                                      wT2 + l * 16384, b2 + l * D, houts[l]);
        hin = houts[l];
    }
    k_final<<<gw, 256, 0, stream>>>(xb, hb1, hb2, hb3, fwTc, fb, out);
}

// Round 10
// 327.107 us; speedup vs baseline: 1.2461x; 1.2461x over previous
//
#include <hip/hip_runtime.h>

#define NNODES 50000
#define NEDGES 640000
#define D 128

typedef unsigned short u16;
typedef unsigned int u32;
typedef __bf16 bf16x8 __attribute__((ext_vector_type(8)));
typedef float f32x4 __attribute__((ext_vector_type(4)));
union AB { uint4 u4; bf16x8 f; };

#define AS1 __attribute__((address_space(1)))
#define AS3 __attribute__((address_space(3)))

// async 16B/lane global->LDS DMA; lds dest = wave-uniform base + lane*16
__device__ __forceinline__ void dma16(const u16* g, u16* l) {
    __builtin_amdgcn_global_load_lds((const AS1 u32*)g, (AS3 u32*)l, 16, 0, 0);
}

__device__ __forceinline__ u16 f2b(float f) {
    u32 u = __float_as_uint(f);
    return (u16)((u + 0x7fffu + ((u >> 16) & 1u)) >> 16);
}
__device__ __forceinline__ u32 pack2(float lo, float hi) {
    return (u32)f2b(lo) | ((u32)f2b(hi) << 16);
}
__device__ __forceinline__ float blo(u32 v) { return __uint_as_float(v << 16); }
__device__ __forceinline__ float bhi(u32 v) { return __uint_as_float(v & 0xffff0000u); }

__device__ __forceinline__ void acc8(float* a, uint4 v) {
    a[0] += blo(v.x); a[1] += bhi(v.x);
    a[2] += blo(v.y); a[3] += bhi(v.y);
    a[4] += blo(v.z); a[5] += bhi(v.z);
    a[6] += blo(v.w); a[7] += bhi(v.w);
}

// ---------------- CSR build ----------------

__global__ void k_hist(const int* __restrict__ dst, int* __restrict__ cnt) {
    int e = blockIdx.x * 256 + threadIdx.x;
    if (e < NEDGES) atomicAdd(&cnt[dst[e]], 1);
}

__global__ void k_scan1(const int* __restrict__ cnt, int* __restrict__ rp,
                        int* __restrict__ bsum) {
    __shared__ int s[256];
    int tid = threadIdx.x;
    int i = blockIdx.x * 256 + tid;
    int v = (i < NNODES) ? cnt[i] : 0;
    s[tid] = v;
    __syncthreads();
    for (int off = 1; off < 256; off <<= 1) {
        int t = (tid >= off) ? s[tid - off] : 0;
        __syncthreads();
        s[tid] += t;
        __syncthreads();
    }
    if (i < NNODES) rp[i] = s[tid] - v;
    if (tid == 255) bsum[blockIdx.x] = s[255];
}

__global__ void k_scan2(int* __restrict__ bsum, int nb) {
    __shared__ int s[256];
    int tid = threadIdx.x;
    int v = (tid < nb) ? bsum[tid] : 0;
    s[tid] = v;
    __syncthreads();
    for (int off = 1; off < 256; off <<= 1) {
        int t = (tid >= off) ? s[tid - off] : 0;
        __syncthreads();
        s[tid] += t;
        __syncthreads();
    }
    if (tid < nb) bsum[tid] = s[tid] - v;
}

__global__ void k_add(int* __restrict__ rp, const int* __restrict__ bsum) {
    int i = blockIdx.x * 256 + threadIdx.x;
    if (i < NNODES) rp[i] += bsum[blockIdx.x];
    if (i == 0) rp[NNODES] = NEDGES;
}

__global__ void k_scatter(const int* __restrict__ src, const int* __restrict__ dst,
                          const int* __restrict__ rp, int* __restrict__ cnt,
                          int* __restrict__ srcs) {
    int e = blockIdx.x * 256 + threadIdx.x;
    if (e < NEDGES) {
        int dn = dst[e];
        int old = atomicSub(&cnt[dn], 1);
        srcs[rp[dn] + old - 1] = src[e];
    }
}

// ---------------- weight prep: fragment-slab layout + x conversion ----------------
// Slab layout per 16KB half (64 cols): slab t=kb*4+quad (t=0..15) holds
// [c=0..63][e=0..7] = W[k=(t>>2)*32+(t&3)*8+e][n=h*64+c]. A b-frag read for
// (colgrp, kb) is 16 lanes x contiguous 16B within one slab: conflict-free.
__global__ void k_prep(const float* __restrict__ W1, const float* __restrict__ W2,
                       const float* __restrict__ fw, const float* __restrict__ x,
                       u16* __restrict__ w1x, u16* __restrict__ w2x,
                       u16* __restrict__ fwx, u32* __restrict__ xb) {
    int idx = blockIdx.x * 256 + threadIdx.x;  // grid covers NNODES*64
    if (idx < 3 * 16384) {
        int l = idx >> 14, r = idx & 16383;
        int h = r >> 13, r2 = r & 8191;
        int t = r2 >> 9, r3 = r2 & 511;
        int c = r3 >> 3, e = r3 & 7;
        int k = (t >> 2) * 32 + (t & 3) * 8 + e;
        int n = h * 64 + c;
        w1x[idx] = f2b(W1[l * 16384 + k * 128 + n]);
        w2x[idx] = f2b(W2[l * 16384 + k * 128 + n]);
    }
    if (idx < 4 * 16384) {
        int chn = idx >> 14, r = idx & 16383;
        int h = r >> 13, r2 = r & 8191;
        int t = r2 >> 9, r3 = r2 & 511;
        int c = r3 >> 3, e = r3 & 7;
        int k = (t >> 2) * 32 + (t & 3) * 8 + e;
        fwx[idx] = f2b(fw[(chn * 128 + k) * 128 + h * 64 + c]);
    }
    if (idx < NNODES * 64) {
        float2 v = ((const float2*)x)[idx];
        xb[idx] = pack2(v.x, v.y);
    }
}

// ---------------- aggregation (unchanged from round 5) ----------------
__global__ void k_agg(const uint4* __restrict__ h4, const int* __restrict__ rp,
                      const int* __restrict__ srcs, const float* __restrict__ epsp,
                      uint4* __restrict__ z4) {
    int tid = threadIdx.x;
    int c = tid & 15;
    int node = (blockIdx.x * 256 + tid) >> 4;
    int gbase = tid & 48;
    float sc = 1.0f + epsp[0];

    uint4 sv = h4[node * 16 + c];
    float acc[8];
    acc[0] = sc * blo(sv.x); acc[1] = sc * bhi(sv.x);
    acc[2] = sc * blo(sv.y); acc[3] = sc * bhi(sv.y);
    acc[4] = sc * blo(sv.z); acc[5] = sc * bhi(sv.z);
    acc[6] = sc * blo(sv.w); acc[7] = sc * bhi(sv.w);

    int beg = rp[node], end = rp[node + 1];
    for (int base = beg; base < end; base += 16) {
        int n = end - base; if (n > 16) n = 16;
        int myidx = (base + c < end) ? srcs[base + c] : 0;
        int j = 0;
        for (; j + 8 <= n; j += 8) {
            int s0 = __shfl(myidx, gbase + j + 0, 64);
            int s1 = __shfl(myidx, gbase + j + 1, 64);
            int s2 = __shfl(myidx, gbase + j + 2, 64);
            int s3 = __shfl(myidx, gbase + j + 3, 64);
            int s4 = __shfl(myidx, gbase + j + 4, 64);
            int s5 = __shfl(myidx, gbase + j + 5, 64);
            int s6 = __shfl(myidx, gbase + j + 6, 64);
            int s7 = __shfl(myidx, gbase + j + 7, 64);
            uint4 v0 = h4[s0 * 16 + c]; uint4 v1 = h4[s1 * 16 + c];
            uint4 v2 = h4[s2 * 16 + c]; uint4 v3 = h4[s3 * 16 + c];
            uint4 v4 = h4[s4 * 16 + c]; uint4 v5 = h4[s5 * 16 + c];
            uint4 v6 = h4[s6 * 16 + c]; uint4 v7 = h4[s7 * 16 + c];
            acc8(acc, v0); acc8(acc, v1); acc8(acc, v2); acc8(acc, v3);
            acc8(acc, v4); acc8(acc, v5); acc8(acc, v6); acc8(acc, v7);
        }
        for (; j + 4 <= n; j += 4) {
            int s0 = __shfl(myidx, gbase + j + 0, 64);
            int s1 = __shfl(myidx, gbase + j + 1, 64);
            int s2 = __shfl(myidx, gbase + j + 2, 64);
            int s3 = __shfl(myidx, gbase + j + 3, 64);
            uint4 v0 = h4[s0 * 16 + c]; uint4 v1 = h4[s1 * 16 + c];
            uint4 v2 = h4[s2 * 16 + c]; uint4 v3 = h4[s3 * 16 + c];
            acc8(acc, v0); acc8(acc, v1); acc8(acc, v2); acc8(acc, v3);
        }
        for (; j < n; ++j) {
            int s0 = __shfl(myidx, gbase + j, 64);
            uint4 v0 = h4[s0 * 16 + c];
            acc8(acc, v0);
        }
    }

    uint4 o;
    o.x = pack2(acc[0], acc[1]); o.y = pack2(acc[2], acc[3]);
    o.z = pack2(acc[4], acc[5]); o.w = pack2(acc[6], acc[7]);
    z4[node * 16 + c] = o;
}

// ---------------- MLP: M-tile 64, col-split waves, DMA-staged slab weights ----------------
// Wave w computes cols {w, 4+w} for all 4 row-strips (B-frag reuse x4).
// W staged in 16KB halves via global_load_lds; b-frag ds_reads conflict-free.
// T round-trips through XOR-swizzled Tb (r5-proven). LDS 32KB.
__launch_bounds__(256, 3)
__global__ void k_mlp(const u16* __restrict__ A, const u16* __restrict__ w1x,
                      const float* __restrict__ b1, const u16* __restrict__ w2x,
                      const float* __restrict__ b2, u16* __restrict__ H) {
    __shared__ __align__(16) u16 Tb[64 * 128];  // 16 KB
    __shared__ __align__(16) u16 wb[8192];      // 16 KB (16 slabs x 512 u16)
    uint4* Tb4 = (uint4*)Tb;
    int tid = threadIdx.x;
    int wave = tid >> 6, lane = tid & 63, l16 = lane & 15, quad = lane >> 4;
    int r0 = blockIdx.x * 64;

    // A-frags: 4 strips x 4 kb, direct global (issued before DMA)
    AB a[4][4];
#pragma unroll
    for (int s = 0; s < 4; ++s) {
        int row = r0 + s * 16 + l16;
#pragma unroll
        for (int kb = 0; kb < 4; ++kb)
            a[s][kb].u4 = (row < NNODES)
                ? *(const uint4*)&A[row * 128 + kb * 32 + quad * 8]
                : make_uint4(0, 0, 0, 0);
    }
    // DMA W1 half0
#pragma unroll
    for (int p = 0; p < 4; ++p) {
        int seg = p * 4 + wave;
        dma16(w1x + seg * 512 + lane * 8, wb + seg * 512);
    }
    __syncthreads();  // drains DMA (vmcnt0 before barrier)

    f32x4 acc[2][4];
#pragma unroll
    for (int h = 0; h < 2; ++h) {
        float bv = b1[(h * 4 + wave) * 16 + l16];
#pragma unroll
        for (int s = 0; s < 4; ++s) acc[h][s] = (f32x4){bv, bv, bv, bv};
    }
    // G1 half0 (cols 0-3; this wave: col=wave)
#pragma unroll
    for (int kb = 0; kb < 4; ++kb) {
        AB b; b.u4 = *(const uint4*)&wb[(kb * 4 + quad) * 512 + (wave * 16 + l16) * 8];
#pragma unroll
        for (int s = 0; s < 4; ++s)
            acc[0][s] = __builtin_amdgcn_mfma_f32_16x16x32_bf16(a[s][kb].f, b.f, acc[0][s], 0, 0, 0);
    }
    __syncthreads();
    // DMA W1 half1
#pragma unroll
    for (int p = 0; p < 4; ++p) {
        int seg = p * 4 + wave;
        dma16(w1x + 8192 + seg * 512 + lane * 8, wb + seg * 512);
    }
    __syncthreads();
    // G1 half1 (cols 4-7; this wave: col=4+wave)
#pragma unroll
    for (int kb = 0; kb < 4; ++kb) {
        AB b; b.u4 = *(const uint4*)&wb[(kb * 4 + quad) * 512 + (wave * 16 + l16) * 8];
#pragma unroll
        for (int s = 0; s < 4; ++s)
            acc[1][s] = __builtin_amdgcn_mfma_f32_16x16x32_bf16(a[s][kb].f, b.f, acc[1][s], 0, 0, 0);
    }

    // T = relu -> Tb (XOR-swizzled scalar stores)
#pragma unroll
    for (int h = 0; h < 2; ++h) {
        int kcol = (h * 4 + wave) * 16 + l16;
        int ch = kcol >> 3;
#pragma unroll
        for (int s = 0; s < 4; ++s)
#pragma unroll
            for (int r = 0; r < 4; ++r) {
                int row = s * 16 + quad * 4 + r;
                Tb[row * 128 + ((ch + row) & 15) * 8 + (kcol & 7)] =
                    f2b(fmaxf(acc[h][s][r], 0.f));
            }
    }
    __syncthreads();

    // DMA W2 half0 + a2-frags from Tb (swizzled, conflict-free)
#pragma unroll
    for (int p = 0; p < 4; ++p) {
        int seg = p * 4 + wave;
        dma16(w2x + seg * 512 + lane * 8, wb + seg * 512);
    }
#pragma unroll
    for (int s = 0; s < 4; ++s) {
        int m = s * 16 + l16;
#pragma unroll
        for (int kb = 0; kb < 4; ++kb)
            a[s][kb].u4 = Tb4[m * 16 + ((kb * 4 + quad + m) & 15)];
    }
    __syncthreads();

#pragma unroll
    for (int h = 0; h < 2; ++h) {
        float bv = b2[(h * 4 + wave) * 16 + l16];
#pragma unroll
        for (int s = 0; s < 4; ++s) acc[h][s] = (f32x4){bv, bv, bv, bv};
    }
    // G2 half0
#pragma unroll
    for (int kb = 0; kb < 4; ++kb) {
        AB b; b.u4 = *(const uint4*)&wb[(kb * 4 + quad) * 512 + (wave * 16 + l16) * 8];
#pragma unroll
        for (int s = 0; s < 4; ++s)
            acc[0][s] = __builtin_amdgcn_mfma_f32_16x16x32_bf16(a[s][kb].f, b.f, acc[0][s], 0, 0, 0);
    }
    __syncthreads();
    // DMA W2 half1
#pragma unroll
    for (int p = 0; p < 4; ++p) {
        int seg = p * 4 + wave;
        dma16(w2x + 8192 + seg * 512 + lane * 8, wb + seg * 512);
    }
    __syncthreads();
    // G2 half1
#pragma unroll
    for (int kb = 0; kb < 4; ++kb) {
        AB b; b.u4 = *(const uint4*)&wb[(kb * 4 + quad) * 512 + (wave * 16 + l16) * 8];
#pragma unroll
        for (int s = 0; s < 4; ++s)
            acc[1][s] = __builtin_amdgcn_mfma_f32_16x16x32_bf16(a[s][kb].f, b.f, acc[1][s], 0, 0, 0);
    }

    // H = relu -> Tb (swizzled; all a2 reads completed before barrier above)
#pragma unroll
    for (int h = 0; h < 2; ++h) {
        int kcol = (h * 4 + wave) * 16 + l16;
        int ch = kcol >> 3;
#pragma unroll
        for (int s = 0; s < 4; ++s)
#pragma unroll
            for (int r = 0; r < 4; ++r) {
                int row = s * 16 + quad * 4 + r;
                Tb[row * 128 + ((ch + row) & 15) * 8 + (kcol & 7)] =
                    f2b(fmaxf(acc[h][s][r], 0.f));
            }
    }
    __syncthreads();

    // coalesced de-swizzle copy Tb -> H (64 rows x 16 chunks = 1024 uint4)
#pragma unroll
    for (int p = 0; p < 4; ++p) {
        int i = p * 256 + tid;
        int r = i >> 4, ch = i & 15;
        int grow = r0 + r;
        if (grow < NNODES)
            *(uint4*)&H[grow * 128 + ch * 8] = Tb4[r * 16 + ((ch + r) & 15)];
    }
}

// ---------------- final: M-tile 64, col-split waves, DMA-staged slab weights ----------------
__launch_bounds__(256, 3)
__global__ void k_final(const u16* __restrict__ xb, const u16* __restrict__ h1,
                        const u16* __restrict__ h2b, const u16* __restrict__ h3,
                        const u16* __restrict__ fwx, const float* __restrict__ fb,
                        float* __restrict__ out) {
    __shared__ __align__(16) u16 wb[8192];  // 16 KB
    int tid = threadIdx.x;
    int wave = tid >> 6, lane = tid & 63, l16 = lane & 15, quad = lane >> 4;
    int r0 = blockIdx.x * 64;

    f32x4 acc[2][4];
#pragma unroll
    for (int h = 0; h < 2; ++h) {
        float bv = fb[(h * 4 + wave) * 16 + l16];
#pragma unroll
        for (int s = 0; s < 4; ++s) acc[h][s] = (f32x4){bv, bv, bv, bv};
    }

    const u16* chin[4] = {xb, h1, h2b, h3};
#pragma unroll
    for (int chn = 0; chn < 4; ++chn) {
        const u16* cp = chin[chn];
        AB a[4][4];
#pragma unroll
        for (int s = 0; s < 4; ++s) {
            int row = r0 + s * 16 + l16;
#pragma unroll
            for (int kb = 0; kb < 4; ++kb)
                a[s][kb].u4 = (row < NNODES)
                    ? *(const uint4*)&cp[row * 128 + kb * 32 + quad * 8]
                    : make_uint4(0, 0, 0, 0);
        }
#pragma unroll
        for (int h = 0; h < 2; ++h) {
            __syncthreads();  // prior wb readers done
#pragma unroll
            for (int p = 0; p < 4; ++p) {
                int seg = p * 4 + wave;
                dma16(fwx + (chn * 2 + h) * 8192 + seg * 512 + lane * 8, wb + seg * 512);
            }
            __syncthreads();  // DMA drained
#pragma unroll
            for (int kb = 0; kb < 4; ++kb) {
                AB b; b.u4 = *(const uint4*)&wb[(kb * 4 + quad) * 512 + (wave * 16 + l16) * 8];
#pragma unroll
                for (int s = 0; s < 4; ++s)
                    acc[h][s] = __builtin_amdgcn_mfma_f32_16x16x32_bf16(a[s][kb].f, b.f, acc[h][s], 0, 0, 0);
            }
        }
    }

#pragma unroll
    for (int h = 0; h < 2; ++h)
#pragma unroll
        for (int s = 0; s < 4; ++s)
#pragma unroll
            for (int r = 0; r < 4; ++r) {
                int row = r0 + s * 16 + quad * 4 + r;
                if (row < NNODES)
                    out[row * 128 + (h * 4 + wave) * 16 + l16] = acc[h][s][r];
            }
}

extern "C" void kernel_launch(void* const* d_in, const int* in_sizes, int n_in,
                              void* d_out, int out_size, void* d_ws, size_t ws_size,
                              hipStream_t stream) {
    const float* x   = (const float*)d_in[0];
    const int*   ei  = (const int*)d_in[1];
    const float* W1  = (const float*)d_in[2];
    const float* b1  = (const float*)d_in[3];
    const float* W2  = (const float*)d_in[4];
    const float* b2  = (const float*)d_in[5];
    const float* eps = (const float*)d_in[6];
    const float* fw  = (const float*)d_in[7];
    const float* fb  = (const float*)d_in[8];
    float* out = (float*)d_out;

    const int* srcA = ei;
    const int* dstA = ei + NEDGES;

    char* p = (char*)d_ws;
    size_t off = 0;
    auto take = [&](size_t bytes) {
        char* r = p + off;
        off = (off + bytes + 255) & ~(size_t)255;
        return r;
    };
    int* rp   = (int*)take((NNODES + 1) * sizeof(int));
    int* cnt  = (int*)take(NNODES * sizeof(int));
    int* bsum = (int*)take(256 * sizeof(int));
    int* srcs = (int*)take(NEDGES * sizeof(int));
    u16* w1x  = (u16*)take(3 * 16384 * sizeof(u16));
    u16* w2x  = (u16*)take(3 * 16384 * sizeof(u16));
    u16* fwx  = (u16*)take(4 * 16384 * sizeof(u16));
    u16* xb   = (u16*)take((size_t)NNODES * D * sizeof(u16));
    u16* zb   = (u16*)take((size_t)NNODES * D * sizeof(u16));
    u16* hb1  = (u16*)take((size_t)NNODES * D * sizeof(u16));
    u16* hb2  = (u16*)take((size_t)NNODES * D * sizeof(u16));
    u16* hb3  = (u16*)take((size_t)NNODES * D * sizeof(u16));
    (void)ws_size; (void)in_sizes; (void)n_in; (void)out_size;

    hipMemsetAsync(cnt, 0, NNODES * sizeof(int), stream);

    int nb = (NNODES + 255) / 256;
    k_hist<<<(NEDGES + 255) / 256, 256, 0, stream>>>(dstA, cnt);
    k_scan1<<<nb, 256, 0, stream>>>(cnt, rp, bsum);
    k_scan2<<<1, 256, 0, stream>>>(bsum, nb);
    k_add<<<nb, 256, 0, stream>>>(rp, bsum);
    k_scatter<<<(NEDGES + 255) / 256, 256, 0, stream>>>(srcA, dstA, rp, cnt, srcs);
    k_prep<<<(NNODES * 64 + 255) / 256, 256, 0, stream>>>(W1, W2, fw, x, w1x, w2x, fwx, (u32*)xb);

    const u16* hin = xb;
    u16* houts[3] = {hb1, hb2, hb3};
    int gm = (NNODES + 63) / 64;  // 782 blocks, 64 rows each
    for (int l = 0; l < 3; ++l) {
        k_agg<<<NNODES * 16 / 256, 256, 0, stream>>>((const uint4*)hin, rp, srcs, eps + l, (uint4*)zb);
        // NOTE: per-layer weight stride is 16384 u16 ELEMENTS (32768 bytes) — r9 bug was l*32768
        k_mlp<<<gm, 256, 0, stream>>>(zb, w1x + l * 16384, b1 + l * D,
                                      w2x + l * 16384, b2 + l * D, houts[l]);
        hin = houts[l];
    }
    k_final<<<gm, 256, 0, stream>>>(xb, hb1, hb2, hb3, fwx, fb, out);
}